// Round 1
// baseline (667.128 us; speedup 1.0000x reference)
//
#include <hip/hip_runtime.h>

// Problem constants (AdditiveAttention): B=32, S=2048, HLEN=VLEN=HID=1024, fp32 in/out.
constexpr int B_   = 32;
constexpr int S_   = 2048;
constexpr int HID_ = 1024;
constexpr int VL_  = 1024;   // VLEN == HLEN == HID == 1024

typedef __attribute__((ext_vector_type(4))) float  f32x4;
typedef __attribute__((ext_vector_type(4))) short  s16x4;
typedef __attribute__((ext_vector_type(8))) short  s16x8;

// fp32 -> bf16 round-to-nearest-even (inputs are normal floats; no NaN handling needed)
__device__ __forceinline__ short f2bf(float f) {
    union { float f; unsigned u; } v; v.f = f;
    unsigned r = v.u + 0x7fffu + ((v.u >> 16) & 1u);
    return (short)(r >> 16);
}

// tanh via exp; saturates correctly at +/-inf. ~1e-7 abs err, negligible vs bf16 noise.
__device__ __forceinline__ float fast_tanh(float x) {
    float e2 = __expf(2.0f * x);
    return 1.0f - 2.0f / (e2 + 1.0f);
}

// ---------------- h_proj = h @ W_w^T + W_b  [B, HID] ----------------
// wave-per-(b,d): 64 lanes reduce K=1024 with float4 loads.
__global__ __launch_bounds__(256) void hproj_kernel(const float* __restrict__ h,
                                                    const float* __restrict__ Ww,
                                                    const float* __restrict__ Wb,
                                                    float* __restrict__ hp) {
    int tid = threadIdx.x;
    int wave = tid >> 6, lane = tid & 63;
    int d = blockIdx.x * 4 + wave;   // grid.x = HID/4
    int b = blockIdx.y;
    const float* wr = Ww + (size_t)d * HID_;
    const float* hr = h  + (size_t)b * HID_;
    float acc = 0.0f;
#pragma unroll
    for (int i = 0; i < 4; i++) {
        float4 a = *(const float4*)(wr + i * 256 + lane * 4);
        float4 x = *(const float4*)(hr + i * 256 + lane * 4);
        acc += a.x * x.x + a.y * x.y + a.z * x.z + a.w * x.w;
    }
#pragma unroll
    for (int o = 32; o; o >>= 1) acc += __shfl_xor(acc, o);
    if (lane == 0) hp[(size_t)b * HID_ + d] = acc + Wb[d];
}

// ---------------- fp32 -> bf16 bulk convert (grid-stride over float4) ----------------
__global__ __launch_bounds__(256) void cvt_kernel(const float* __restrict__ src,
                                                  short* __restrict__ dst, size_t n4) {
    size_t i = (size_t)blockIdx.x * blockDim.x + threadIdx.x;
    size_t stride = (size_t)gridDim.x * blockDim.x;
    for (; i < n4; i += stride) {
        float4 x = ((const float4*)src)[i];
        s16x4 y;
        y.x = f2bf(x.x); y.y = f2bf(x.y); y.z = f2bf(x.z); y.w = f2bf(x.w);
        ((s16x4*)dst)[i] = y;
    }
}

// ---------------- fused e kernel: e[b,s] += sum_d w[d]*tanh(hp[b,d] + (V @ U^T)[s,d]) ----
// Block: 256 thr (4 waves, 2x2), tile M=128 (s) x N=128 (d), BK=32, 16x16x32 bf16 MFMA.
// Grid: (HID/128=8, S/128=16, B=32). Epilogue reduces each C tile over d into e partials.
template <typename AT>   // AT = short (bf16 pre-converted) or float (convert on the fly)
__global__ __launch_bounds__(256) void e_kernel(const AT* __restrict__ Vm,
                                                const AT* __restrict__ Um,
                                                const float* __restrict__ hp,
                                                const float* __restrict__ ww,
                                                float* __restrict__ e) {
    __shared__ short As[128][40];   // +8 pad: 80B row stride -> 2-way LDS aliasing (free)
    __shared__ short Bs[128][40];

    int tid = threadIdx.x;
    int b  = blockIdx.z;
    int d0 = blockIdx.x * 128;
    int s0 = blockIdx.y * 128;
    int wave = tid >> 6, lane = tid & 63;
    int wm = wave >> 1, wn = wave & 1;       // 2x2 waves, each 64x64
    int col = lane & 15, quad = lane >> 4;

    f32x4 zero = {0.f, 0.f, 0.f, 0.f};
    f32x4 acc[4][4];
#pragma unroll
    for (int i = 0; i < 4; i++)
#pragma unroll
        for (int j = 0; j < 4; j++) acc[i][j] = zero;

    const AT* Abase = Vm + ((size_t)b * S_ + s0) * (size_t)VL_;
    const AT* Bbase = Um + (size_t)d0 * (size_t)VL_;

    for (int k0 = 0; k0 < VL_; k0 += 32) {
        // ---- stage A (V rows) and B (U_w rows) into LDS as bf16 [row][k] ----
        if constexpr (sizeof(AT) == 4) {
            int k4 = tid & 7, rb = tid >> 3;            // 8 float4-groups x 32 row-slots
#pragma unroll
            for (int i = 0; i < 4; i++) {
                int r = rb + 32 * i;
                const float* pa = (const float*)Abase + (size_t)r * VL_ + k0 + k4 * 4;
                float4 x = *(const float4*)pa;
                s16x4 ya; ya.x = f2bf(x.x); ya.y = f2bf(x.y); ya.z = f2bf(x.z); ya.w = f2bf(x.w);
                *(s16x4*)&As[r][k4 * 4] = ya;
                const float* pb = (const float*)Bbase + (size_t)r * VL_ + k0 + k4 * 4;
                float4 y = *(const float4*)pb;
                s16x4 yb; yb.x = f2bf(y.x); yb.y = f2bf(y.y); yb.z = f2bf(y.z); yb.w = f2bf(y.w);
                *(s16x4*)&Bs[r][k4 * 4] = yb;
            }
        } else {
            int k8 = tid & 3, rb = tid >> 2;            // 4 short8-groups x 64 row-slots
#pragma unroll
            for (int i = 0; i < 2; i++) {
                int r = rb + 64 * i;
                *(s16x8*)&As[r][k8 * 8] =
                    *(const s16x8*)((const short*)Abase + (size_t)r * VL_ + k0 + k8 * 8);
                *(s16x8*)&Bs[r][k8 * 8] =
                    *(const s16x8*)((const short*)Bbase + (size_t)r * VL_ + k0 + k8 * 8);
            }
        }
        __syncthreads();

        // ---- fragments: A[m=lane&15][k=quad*8+j], B^T same layout (m89/m92-verified) ----
        s16x8 a8[4], b8[4];
#pragma unroll
        for (int tm = 0; tm < 4; tm++)
            a8[tm] = *(const s16x8*)&As[wm * 64 + tm * 16 + col][quad * 8];
#pragma unroll
        for (int tn = 0; tn < 4; tn++)
            b8[tn] = *(const s16x8*)&Bs[wn * 64 + tn * 16 + col][quad * 8];
#pragma unroll
        for (int tm = 0; tm < 4; tm++)
#pragma unroll
            for (int tn = 0; tn < 4; tn++)
                acc[tm][tn] = __builtin_amdgcn_mfma_f32_16x16x32_bf16(
                    a8[tm], b8[tn], acc[tm][tn], 0, 0, 0);
        __syncthreads();
    }

    // ---- epilogue: C/D layout col=lane&15, row=quad*4+reg (m89-verified).
    // t = w[d]*tanh(hp[d]+C[s,d]); sum over this block's 128 d's -> atomicAdd into e[b,s].
    float wv[4], hv[4];
#pragma unroll
    for (int tn = 0; tn < 4; tn++) {
        int d = d0 + wn * 64 + tn * 16 + col;
        wv[tn] = ww[d];
        hv[tn] = hp[(size_t)b * HID_ + d];
    }
#pragma unroll
    for (int tm = 0; tm < 4; tm++) {
#pragma unroll
        for (int reg = 0; reg < 4; reg++) {
            float p = 0.0f;
#pragma unroll
            for (int tn = 0; tn < 4; tn++)
                p += wv[tn] * fast_tanh(hv[tn] + acc[tm][tn][reg]);
            // reduce across the 16 cols (lanes sharing this row)
            p += __shfl_xor(p, 1);
            p += __shfl_xor(p, 2);
            p += __shfl_xor(p, 4);
            p += __shfl_xor(p, 8);
            if (col == 0) {
                int s = s0 + wm * 64 + tm * 16 + quad * 4 + reg;
                atomicAdd(&e[(size_t)b * S_ + s], p);
            }
        }
    }
}

// ---------------- softmax over s (in place), one block per b ----------------
__global__ __launch_bounds__(256) void softmax_kernel(float* __restrict__ e) {
    int b = blockIdx.x, tid = threadIdx.x;
    float* row = e + (size_t)b * S_;
    float v[8];
    float m = -1e30f;
#pragma unroll
    for (int i = 0; i < 8; i++) { v[i] = row[tid + i * 256]; m = fmaxf(m, v[i]); }
#pragma unroll
    for (int o = 32; o; o >>= 1) m = fmaxf(m, __shfl_xor(m, o));
    __shared__ float rm[4], rs[4];
    int wave = tid >> 6, lane = tid & 63;
    if (lane == 0) rm[wave] = m;
    __syncthreads();
    m = fmaxf(fmaxf(rm[0], rm[1]), fmaxf(rm[2], rm[3]));
    float s = 0.0f;
#pragma unroll
    for (int i = 0; i < 8; i++) { v[i] = __expf(v[i] - m); s += v[i]; }
#pragma unroll
    for (int o = 32; o; o >>= 1) s += __shfl_xor(s, o);
    if (lane == 0) rs[wave] = s;
    __syncthreads();
    s = rs[0] + rs[1] + rs[2] + rs[3];
    float inv = 1.0f / s;
#pragma unroll
    for (int i = 0; i < 8; i++) row[tid + i * 256] = v[i] * inv;
}

// ---------------- out[b,v] = sum_s beta[b,s] * V[b,s,v]  (fp32 V, HBM-bound) ----------
__global__ __launch_bounds__(256) void out_kernel(const float* __restrict__ beta,
                                                  const float* __restrict__ V,
                                                  float* __restrict__ out) {
    int b = blockIdx.x, sc = blockIdx.y;    // grid (B, 16), s-chunk = 128
    int v4 = threadIdx.x;                    // float4 index: covers VLEN=1024
    const float* Vb = V + ((size_t)b * S_ + (size_t)sc * 128) * VL_;
    const float* bb = beta + (size_t)b * S_ + (size_t)sc * 128;
    float ax = 0.f, ay = 0.f, az = 0.f, aw = 0.f;
    for (int s = 0; s < 128; s++) {
        float w = bb[s];
        float4 x = *(const float4*)(Vb + (size_t)s * VL_ + v4 * 4);
        ax += w * x.x; ay += w * x.y; az += w * x.z; aw += w * x.w;
    }
    float* o = out + (size_t)b * VL_ + v4 * 4;
    atomicAdd(o + 0, ax);
    atomicAdd(o + 1, ay);
    atomicAdd(o + 2, az);
    atomicAdd(o + 3, aw);
}

extern "C" void kernel_launch(void* const* d_in, const int* in_sizes, int n_in,
                              void* d_out, int out_size, void* d_ws, size_t ws_size,
                              hipStream_t stream) {
    const float* h  = (const float*)d_in[0];
    const float* V  = (const float*)d_in[1];
    const float* Ww = (const float*)d_in[2];
    const float* Wb = (const float*)d_in[3];
    const float* Uw = (const float*)d_in[4];
    const float* ww = (const float*)d_in[5];
    float* out = (float*)d_out;

    char* ws = (char*)d_ws;
    float* hp = (float*)ws;                               // 32*1024*4   = 128 KiB
    float* e  = (float*)(ws + 131072);                    // 32*2048*4   = 256 KiB
    short* Vb16 = (short*)(ws + 393216);                  // 32*2048*1024*2 = 128 MiB
    short* Ub16 = Vb16 + (size_t)B_ * S_ * VL_;           // 1024*1024*2 = 2 MiB
    size_t need = 393216 + ((size_t)B_ * S_ * VL_ + (size_t)HID_ * VL_) * 2;
    bool bf16path = (ws_size >= need);                    // same branch every call

    hipMemsetAsync(e, 0, (size_t)B_ * S_ * 4, stream);
    hipMemsetAsync(out, 0, (size_t)out_size * 4, stream);

    hproj_kernel<<<dim3(HID_ / 4, B_), 256, 0, stream>>>(h, Ww, Wb, hp);

    if (bf16path) {
        cvt_kernel<<<2048, 256, 0, stream>>>(V, Vb16, (size_t)B_ * S_ * VL_ / 4);
        cvt_kernel<<<256, 256, 0, stream>>>(Uw, Ub16, (size_t)HID_ * VL_ / 4);
        e_kernel<short><<<dim3(HID_ / 128, S_ / 128, B_), 256, 0, stream>>>(
            Vb16, Ub16, hp, ww, e);
    } else {
        e_kernel<float><<<dim3(HID_ / 128, S_ / 128, B_), 256, 0, stream>>>(
            V, Uw, hp, ww, e);
    }

    softmax_kernel<<<B_, 256, 0, stream>>>(e);
    out_kernel<<<dim3(B_, S_ / 128), 256, 0, stream>>>(e, V, out);
}